// Round 1
// baseline (246.474 us; speedup 1.0000x reference)
//
#include <hip/hip_runtime.h>
#include <math.h>

// Problem constants (from reference): N=65536 rows, D=512 features, K=5 centroids.
#define LFR_N 65536
#define LFR_D 512
#define LFR_K 5

// One wave (64 lanes) per row; lane owns 8 contiguous d's -> float4 x2 coalesced.
// Centroids/alpha/sigmoid(w) register-resident, amortized via grid-stride row loop.
__global__ __launch_bounds__(256) void lfr_kernel(
    const float* __restrict__ x,        // (N, D)
    const float* __restrict__ alpha,    // (D,)
    const float* __restrict__ w,        // (K, 1)
    const float* __restrict__ cent,     // (K, D)
    float* __restrict__ out_map,        // (N, K)
    float* __restrict__ out_rec,        // (N, D)
    float* __restrict__ out_pred)       // (N,)
{
    const int lane           = threadIdx.x & 63;
    const int wave_in_block  = threadIdx.x >> 6;
    const int waves_per_blk  = blockDim.x >> 6;
    const int wave_id        = blockIdx.x * waves_per_blk + wave_in_block;
    const int num_waves      = gridDim.x * waves_per_blk;

    const int d0 = lane * 8;  // this lane's 8 feature indices

    // ---- per-lane constants (L2-hit loads, once per wave) ----
    float al[8];
    {
        float4 a0 = *(const float4*)(alpha + d0);
        float4 a1 = *(const float4*)(alpha + d0 + 4);
        al[0]=a0.x; al[1]=a0.y; al[2]=a0.z; al[3]=a0.w;
        al[4]=a1.x; al[5]=a1.y; al[6]=a1.z; al[7]=a1.w;
    }
    float c[LFR_K][8];
    #pragma unroll
    for (int k = 0; k < LFR_K; ++k) {
        float4 c0 = *(const float4*)(cent + k * LFR_D + d0);
        float4 c1 = *(const float4*)(cent + k * LFR_D + d0 + 4);
        c[k][0]=c0.x; c[k][1]=c0.y; c[k][2]=c0.z; c[k][3]=c0.w;
        c[k][4]=c1.x; c[k][5]=c1.y; c[k][6]=c1.z; c[k][7]=c1.w;
    }
    float sigw[LFR_K];
    #pragma unroll
    for (int k = 0; k < LFR_K; ++k)
        sigw[k] = 1.0f / (1.0f + __expf(-w[k]));

    for (int row = wave_id; row < LFR_N; row += num_waves) {
        // ---- load this lane's 8 x values (coalesced) ----
        const float* xr = x + (size_t)row * LFR_D + d0;
        float xv[8];
        {
            float4 x0 = *(const float4*)(xr);
            float4 x1 = *(const float4*)(xr + 4);
            xv[0]=x0.x; xv[1]=x0.y; xv[2]=x0.z; xv[3]=x0.w;
            xv[4]=x1.x; xv[5]=x1.y; xv[6]=x1.z; xv[7]=x1.w;
        }

        // ---- partial weighted squared distances ----
        float dist[LFR_K];
        #pragma unroll
        for (int k = 0; k < LFR_K; ++k) {
            float acc = 0.0f;
            #pragma unroll
            for (int j = 0; j < 8; ++j) {
                float df = xv[j] - c[k][j];
                acc = fmaf(al[j] * df, df, acc);
            }
            dist[k] = acc;
        }

        // ---- wave reduction (64 lanes) ----
        #pragma unroll
        for (int off = 32; off > 0; off >>= 1) {
            #pragma unroll
            for (int k = 0; k < LFR_K; ++k)
                dist[k] += __shfl_xor(dist[k], off);
        }

        // ---- softmax over K (wave-uniform, computed redundantly per lane) ----
        float mx = dist[0];
        #pragma unroll
        for (int k = 1; k < LFR_K; ++k) mx = fmaxf(mx, dist[k]);
        float e[LFR_K], s = 0.0f;
        #pragma unroll
        for (int k = 0; k < LFR_K; ++k) { e[k] = __expf(dist[k] - mx); s += e[k]; }
        float inv = 1.0f / s;
        float m[LFR_K];
        #pragma unroll
        for (int k = 0; k < LFR_K; ++k) m[k] = e[k] * inv;

        // ---- reconstruction: r[d] = sum_k m[k] * c[k][d] ----
        float r[8];
        #pragma unroll
        for (int j = 0; j < 8; ++j) {
            float acc = m[0] * c[0][j];
            #pragma unroll
            for (int k = 1; k < LFR_K; ++k) acc = fmaf(m[k], c[k][j], acc);
            r[j] = acc;
        }
        float* rr = out_rec + (size_t)row * LFR_D + d0;
        *(float4*)(rr)     = make_float4(r[0], r[1], r[2], r[3]);
        *(float4*)(rr + 4) = make_float4(r[4], r[5], r[6], r[7]);

        // ---- mapping + pred ----
        if (lane < LFR_K) out_map[(size_t)row * LFR_K + lane] = m[lane];
        if (lane == 0) {
            float p = 0.0f;
            #pragma unroll
            for (int k = 0; k < LFR_K; ++k) p = fmaf(m[k], sigw[k], p);
            out_pred[row] = p;
        }
    }
}

extern "C" void kernel_launch(void* const* d_in, const int* in_sizes, int n_in,
                              void* d_out, int out_size, void* d_ws, size_t ws_size,
                              hipStream_t stream) {
    const float* x     = (const float*)d_in[0];   // (N, D)
    // d_in[1] = is_protected — unused by the reference computation
    const float* alpha = (const float*)d_in[2];   // (D,)
    const float* w     = (const float*)d_in[3];   // (K, 1)
    const float* cent  = (const float*)d_in[4];   // (K, D)

    float* out   = (float*)d_out;
    float* o_map = out;                                         // N*K
    float* o_rec = out + (size_t)LFR_N * LFR_K;                 // N*D
    float* o_prd = out + (size_t)LFR_N * LFR_K + (size_t)LFR_N * LFR_D;  // N

    // 2048 blocks x 256 threads = 8192 waves -> 8 rows per wave (grid-stride).
    dim3 grid(2048), block(256);
    lfr_kernel<<<grid, block, 0, stream>>>(x, alpha, w, cent, o_map, o_rec, o_prd);
}